// Round 1
// baseline (162.738 us; speedup 1.0000x reference)
//
#include <hip/hip_runtime.h>
#include <stdint.h>

// Problem: B=2, S=2048, D=1024, H=16, DH=64. fp32 in/out, bf16 MFMA inside.

typedef __attribute__((ext_vector_type(8))) short bf16x8;   // 8 bf16 = 4 VGPR
typedef __attribute__((ext_vector_type(4))) float f32x4;    // MFMA C/D

__device__ __forceinline__ uint16_t f2bf(float f) {
  union { float f; uint32_t u; } c; c.f = f;
  uint32_t u = c.u;
  return (uint16_t)((u + 0x7fffu + ((u >> 16) & 1u)) >> 16);  // RNE
}

__device__ __forceinline__ void gload_lds16(const void* g, void* l) {
  __builtin_amdgcn_global_load_lds(
      (const __attribute__((address_space(1))) uint32_t*)g,
      (__attribute__((address_space(3))) uint32_t*)l, 16, 0, 0);
}

// Stage 8 rows x 64 cols (bf16) into LDS tile rows [r0..r0+8), pitch 128B.
// XOR-swizzle st: element (row,col) lands at byte row*128 + ((col/8)*16 ^ ((row&7)<<4)) + (col%8)*2.
// global_load_lds writes linearly (base + lane*16), so we pre-swizzle the SOURCE granule.
// Requires r0 % 8 == 0.
__device__ __forceinline__ void stage8(const uint16_t* gbase /*row r0, col 0*/,
                                       int pitch /*elems*/,
                                       uint16_t* lds_r0 /*&tile[r0*64], wave-uniform*/,
                                       int lane) {
  int r = lane >> 3;            // 0..7 row within group
  int gcol = lane & 7;          // 16B granule within row
  int gsrc = gcol ^ r;          // involution; r == (row&7) since r0%8==0
  const uint16_t* src = gbase + (size_t)r * pitch + gsrc * 8;
  gload_lds16(src, lds_r0);
}

// Read an 8-element k-contiguous MFMA fragment (A or B operand) from a swizzled
// [rows][64] bf16 LDS tile. granule = ks*4 + (lane>>4); k-slots are a consistent
// permutation across both operands, so MFMA result is exact regardless of HW k-order.
__device__ __forceinline__ bf16x8 frag_read(const uint16_t* tile, int row, int granule) {
  int off = row * 128 + ((granule << 4) ^ ((row & 7) << 4));
  return *(const bf16x8*)((const char*)tile + off);
}

// ---------------- kernel 0a: fp32 -> bf16 convert of q / kv inputs ----------------
__global__ __launch_bounds__(256) void k_convert(const float* __restrict__ q,
                                                 const float* __restrict__ kv,
                                                 uint16_t* __restrict__ oq,
                                                 uint16_t* __restrict__ okv) {
  const float* src = blockIdx.y ? kv : q;
  uint16_t* dst = blockIdx.y ? okv : oq;
  size_t i = ((size_t)blockIdx.x * 256 + threadIdx.x) * 8;
  float4 a = *(const float4*)(src + i);
  float4 b = *(const float4*)(src + i + 4);
  uint16_t r[8];
  r[0] = f2bf(a.x); r[1] = f2bf(a.y); r[2] = f2bf(a.z); r[3] = f2bf(a.w);
  r[4] = f2bf(b.x); r[5] = f2bf(b.y); r[6] = f2bf(b.z); r[7] = f2bf(b.w);
  *(uint4*)(dst + i) = *(uint4*)r;
}

// ---------------- kernel 0b: weight transpose W(h,d,n) fp32 -> Wt(mat,h,n,d) bf16 ----------------
__global__ __launch_bounds__(256) void k_wtrans(const float* __restrict__ Wq,
                                                const float* __restrict__ Wk,
                                                const float* __restrict__ Wv,
                                                uint16_t* __restrict__ Wt) {
  __shared__ uint16_t t[64][72];           // [n][d-local], padded
  int mat = blockIdx.y >> 4;
  int h = blockIdx.y & 15;
  int d0 = blockIdx.x * 64;
  const float* W = (mat == 0) ? Wq : (mat == 1) ? Wk : Wv;
  int tid = threadIdx.x;
  for (int p = 0; p < 4; p++) {
    int idx = tid + p * 256;               // 0..1023 float4s
    int row = idx >> 4;                    // d-local 0..63
    int c4 = idx & 15;                     // n-chunk of 4
    float4 v = *(const float4*)(W + ((size_t)h * 1024 + d0 + row) * 64 + c4 * 4);
    t[c4 * 4 + 0][row] = f2bf(v.x);
    t[c4 * 4 + 1][row] = f2bf(v.y);
    t[c4 * 4 + 2][row] = f2bf(v.z);
    t[c4 * 4 + 3][row] = f2bf(v.w);
  }
  __syncthreads();
  int n = tid >> 2, dc = tid & 3;
  uint16_t tmp[16];
  for (int i = 0; i < 16; i++) tmp[i] = t[n][dc * 16 + i];
  uint16_t* dst = Wt + ((size_t)(mat * 16 + h) * 64 + n) * 1024 + d0 + dc * 16;
  *(uint4*)(dst) = *(uint4*)(tmp);
  *(uint4*)(dst + 8) = *(uint4*)(tmp + 8);
}

// ---------------- kernel 1: QKV projection GEMM ----------------
// Per block: 128(M) x 64(N=DH) output for one (mat,h). K=1024, BK=64, double-buffered.
// Q,K stored (b,h,s,dh) bf16;  V stored transposed (b,h,dh,s) bf16 for the PV step.
__global__ __launch_bounds__(256, 2) void k_proj(const uint16_t* __restrict__ Xq,
                                                 const uint16_t* __restrict__ Xkv,
                                                 const uint16_t* __restrict__ Wt,
                                                 const float* __restrict__ bq,
                                                 const float* __restrict__ bk,
                                                 const float* __restrict__ bv,
                                                 uint16_t* __restrict__ Qm,
                                                 uint16_t* __restrict__ Km,
                                                 uint16_t* __restrict__ Vtm) {
  __shared__ uint16_t At[2][128 * 64];
  __shared__ uint16_t Bt[2][64 * 64];
  int mb = blockIdx.x;
  int mat = blockIdx.y >> 4;
  int h = blockIdx.y & 15;
  int tid = threadIdx.x, w = tid >> 6, lane = tid & 63;
  const uint16_t* X = (mat == 0) ? Xq : Xkv;
  const uint16_t* Wh = Wt + (size_t)(mat * 16 + h) * (64 * 1024);
  const float* bias = (mat == 0) ? bq : (mat == 1) ? bk : bv;
  int m0 = mb * 128;
  int rgrp = lane >> 4, cl = lane & 15;

  f32x4 acc[2][4];
  for (int mf = 0; mf < 2; mf++)
    for (int nf = 0; nf < 4; nf++)
      for (int j = 0; j < 4; j++) acc[mf][nf][j] = 0.0f;

  // prologue: stage kt=0
  for (int i = 0; i < 4; i++) {
    int r0 = w * 32 + i * 8;
    stage8(X + (size_t)(m0 + r0) * 1024, 1024, &At[0][r0 * 64], lane);
  }
  for (int i = 0; i < 2; i++) {
    int r0 = w * 16 + i * 8;
    stage8(Wh + (size_t)r0 * 1024, 1024, &Bt[0][r0 * 64], lane);
  }

  for (int kt = 0; kt < 16; kt++) {
    __syncthreads();           // staged tile kt ready (implicit vmcnt drain)
    if (kt < 15) {
      int nb = (kt + 1) & 1, k0 = (kt + 1) * 64;
      for (int i = 0; i < 4; i++) {
        int r0 = w * 32 + i * 8;
        stage8(X + (size_t)(m0 + r0) * 1024 + k0, 1024, &At[nb][r0 * 64], lane);
      }
      for (int i = 0; i < 2; i++) {
        int r0 = w * 16 + i * 8;
        stage8(Wh + (size_t)r0 * 1024 + k0, 1024, &Bt[nb][r0 * 64], lane);
      }
    }
    const uint16_t* a_t = At[kt & 1];
    const uint16_t* b_t = Bt[kt & 1];
    bf16x8 af[2][2], bfr[4][2];
    for (int mf = 0; mf < 2; mf++)
      for (int ks = 0; ks < 2; ks++)
        af[mf][ks] = frag_read(a_t, w * 32 + mf * 16 + cl, ks * 4 + rgrp);
    for (int nf = 0; nf < 4; nf++)
      for (int ks = 0; ks < 2; ks++)
        bfr[nf][ks] = frag_read(b_t, nf * 16 + cl, ks * 4 + rgrp);
    for (int mf = 0; mf < 2; mf++)
      for (int nf = 0; nf < 4; nf++)
        for (int ks = 0; ks < 2; ks++)
          acc[mf][nf] = __builtin_amdgcn_mfma_f32_16x16x32_bf16(af[mf][ks], bfr[nf][ks], acc[mf][nf], 0, 0, 0);
  }

  // epilogue: add bias, write bf16. C/D: col=lane&15, row=(lane>>4)*4+j (verified layout)
  for (int mf = 0; mf < 2; mf++)
    for (int nf = 0; nf < 4; nf++) {
      int col = nf * 16 + cl;
      float bb = bias[h * 64 + col];
      if (mat < 2) {
        uint16_t* dstbuf = (mat == 0) ? Qm : Km;
        for (int j = 0; j < 4; j++) {
          int row = m0 + w * 32 + mf * 16 + rgrp * 4 + j;
          int b = row >> 11, s = row & 2047;
          dstbuf[((size_t)(b * 16 + h) * 2048 + s) * 64 + col] = f2bf(acc[mf][nf][j] + bb);
        }
      } else {
        int row0 = m0 + w * 32 + mf * 16 + rgrp * 4;
        int b = row0 >> 11, s0 = row0 & 2047;
        uint16_t pk[4];
        for (int j = 0; j < 4; j++) pk[j] = f2bf(acc[mf][nf][j] + bb);
        uint16_t* dst = Vtm + ((size_t)(b * 16 + h) * 64 + col) * 2048 + s0;
        *(uint64_t*)dst = *(uint64_t*)pk;   // 4 consecutive s, 8B aligned
      }
    }
}

// ---------------- kernel 2: flash attention ----------------
// Block: (q-block of 128, bh). 4 waves x 32 q-rows. KVBLK=64, K/V double-buffered.
__global__ __launch_bounds__(256, 2) void k_attn(const uint16_t* __restrict__ Qm,
                                                 const uint16_t* __restrict__ Km,
                                                 const uint16_t* __restrict__ Vtm,
                                                 const float* __restrict__ mask,
                                                 float* __restrict__ out) {
  __shared__ uint16_t Kt[2][64 * 64];
  __shared__ uint16_t Vt[2][64 * 64];
  __shared__ uint16_t Pt[128 * 64];
  int qb = blockIdx.x, bh = blockIdx.y;
  int b = bh >> 4, h = bh & 15;
  int tid = threadIdx.x, w = tid >> 6, lane = tid & 63;
  const uint16_t* Qbh = Qm + (size_t)bh * (2048 * 64);
  const uint16_t* Kbh = Km + (size_t)bh * (2048 * 64);
  const uint16_t* Vbh = Vtm + (size_t)bh * (64 * 2048);
  const float* maskb = mask + (size_t)b * (2048 * 2048);
  int q0 = qb * 128 + w * 32;
  int rgrp = lane >> 4, cl = lane & 15;

  // Q fragments direct from global (bf16, k-contiguous), held in registers for all tiles
  bf16x8 qf[2][2];
  for (int mf = 0; mf < 2; mf++)
    for (int ks = 0; ks < 2; ks++)
      qf[mf][ks] = *(const bf16x8*)(Qbh + (size_t)(q0 + mf * 16 + cl) * 64 + ks * 32 + rgrp * 8);

  f32x4 oacc[2][4];
  float mrow[2][4], lrow[2][4];
  for (int mf = 0; mf < 2; mf++)
    for (int j = 0; j < 4; j++) { mrow[mf][j] = -1e30f; lrow[mf][j] = 0.0f; }
  for (int mf = 0; mf < 2; mf++)
    for (int nf = 0; nf < 4; nf++)
      for (int j = 0; j < 4; j++) oacc[mf][nf][j] = 0.0f;

  // prologue: stage tile 0
  for (int i = 0; i < 2; i++) {
    int r0 = w * 16 + i * 8;
    stage8(Kbh + (size_t)r0 * 64, 64, &Kt[0][r0 * 64], lane);
    stage8(Vbh + (size_t)r0 * 2048, 2048, &Vt[0][r0 * 64], lane);
  }

  for (int ti = 0; ti < 32; ti++) {
    __syncthreads();           // tile ti staged; prev tile's LDS reads done
    if (ti < 31) {
      int nb = (ti + 1) & 1, t0n = (ti + 1) * 64;
      for (int i = 0; i < 2; i++) {
        int r0 = w * 16 + i * 8;
        stage8(Kbh + (size_t)(t0n + r0) * 64, 64, &Kt[nb][r0 * 64], lane);
        stage8(Vbh + (size_t)r0 * 2048 + t0n, 2048, &Vt[nb][r0 * 64], lane);
      }
    }
    const uint16_t* kt = Kt[ti & 1];
    const uint16_t* vt = Vt[ti & 1];
    int t0 = ti * 64;

    // S = Q K^T
    f32x4 sc[2][4];
    for (int mf = 0; mf < 2; mf++)
      for (int nf = 0; nf < 4; nf++)
        for (int j = 0; j < 4; j++) sc[mf][nf][j] = 0.0f;
    bf16x8 kf[4][2];
    for (int nf = 0; nf < 4; nf++)
      for (int ks = 0; ks < 2; ks++)
        kf[nf][ks] = frag_read(kt, nf * 16 + cl, ks * 4 + rgrp);
    for (int mf = 0; mf < 2; mf++)
      for (int nf = 0; nf < 4; nf++)
        for (int ks = 0; ks < 2; ks++)
          sc[mf][nf] = __builtin_amdgcn_mfma_f32_16x16x32_bf16(qf[mf][ks], kf[nf][ks], sc[mf][nf], 0, 0, 0);

    // scale + mask
    for (int mf = 0; mf < 2; mf++)
      for (int nf = 0; nf < 4; nf++)
        for (int j = 0; j < 4; j++) {
          size_t row = q0 + mf * 16 + rgrp * 4 + j;
          sc[mf][nf][j] = sc[mf][nf][j] * 0.125f + maskb[row * 2048 + t0 + nf * 16 + cl];
        }

    // row max (over 64 t: 4 nf local + 16-lane shuffle reduce)
    float pm[2][4];
    for (int mf = 0; mf < 2; mf++)
      for (int j = 0; j < 4; j++) {
        float v = sc[mf][0][j];
        for (int nf = 1; nf < 4; nf++) v = fmaxf(v, sc[mf][nf][j]);
        pm[mf][j] = v;
      }
    for (int d = 1; d < 16; d <<= 1)
      for (int mf = 0; mf < 2; mf++)
        for (int j = 0; j < 4; j++)
          pm[mf][j] = fmaxf(pm[mf][j], __shfl_xor(pm[mf][j], d, 64));

    // online rescale
    float fac[2][4];
    for (int mf = 0; mf < 2; mf++)
      for (int j = 0; j < 4; j++) {
        float mn = fmaxf(mrow[mf][j], pm[mf][j]);
        fac[mf][j] = __expf(mrow[mf][j] - mn);
        mrow[mf][j] = mn;
        lrow[mf][j] *= fac[mf][j];
      }
    for (int mf = 0; mf < 2; mf++)
      for (int nf = 0; nf < 4; nf++)
        for (int j = 0; j < 4; j++) oacc[mf][nf][j] *= fac[mf][j];

    // P = exp(S - m); write to swizzled LDS; accumulate row sums
    float ps[2][4];
    for (int mf = 0; mf < 2; mf++)
      for (int j = 0; j < 4; j++) ps[mf][j] = 0.0f;
    for (int mf = 0; mf < 2; mf++)
      for (int nf = 0; nf < 4; nf++)
        for (int j = 0; j < 4; j++) {
          float p = __expf(sc[mf][nf][j] - mrow[mf][j]);
          ps[mf][j] += p;
          int rl = w * 32 + mf * 16 + rgrp * 4 + j;
          int c = nf * 16 + cl;
          int off = rl * 128 + ((((c >> 3) << 4)) ^ ((rl & 7) << 4)) + (c & 7) * 2;
          *(uint16_t*)((char*)Pt + off) = f2bf(p);
        }
    for (int d = 1; d < 16; d <<= 1)
      for (int mf = 0; mf < 2; mf++)
        for (int j = 0; j < 4; j++) ps[mf][j] += __shfl_xor(ps[mf][j], d, 64);
    for (int mf = 0; mf < 2; mf++)
      for (int j = 0; j < 4; j++) lrow[mf][j] += ps[mf][j];

    // compiler barrier: order P stores before P fragment loads (same-wave DS ops are
    // in-order in HW; this stops TBAA/scheduler from hoisting the vector loads)
    asm volatile("" ::: "memory");

    // O += P V   (k-slots over t, same permutation both operands)
    bf16x8 pf[2][2], vf[4][2];
    for (int mf = 0; mf < 2; mf++)
      for (int ks = 0; ks < 2; ks++)
        pf[mf][ks] = frag_read(Pt, w * 32 + mf * 16 + cl, ks * 4 + rgrp);
    for (int nf = 0; nf < 4; nf++)
      for (int ks = 0; ks < 2; ks++)
        vf[nf][ks] = frag_read(vt, nf * 16 + cl, ks * 4 + rgrp);
    for (int mf = 0; mf < 2; mf++)
      for (int nf = 0; nf < 4; nf++)
        for (int ks = 0; ks < 2; ks++)
          oacc[mf][nf] = __builtin_amdgcn_mfma_f32_16x16x32_bf16(pf[mf][ks], vf[nf][ks], oacc[mf][nf], 0, 0, 0);
  }

  // epilogue: out[b][s][h*64+col] = oacc / l   (fp32)
  for (int mf = 0; mf < 2; mf++)
    for (int nf = 0; nf < 4; nf++)
      for (int j = 0; j < 4; j++) {
        int row = q0 + mf * 16 + rgrp * 4 + j;
        int col = nf * 16 + cl;
        out[((size_t)b * 2048 + row) * 1024 + h * 64 + col] = oacc[mf][nf][j] / lrow[mf][j];
      }
}

extern "C" void kernel_launch(void* const* d_in, const int* in_sizes, int n_in,
                              void* d_out, int out_size, void* d_ws, size_t ws_size,
                              hipStream_t stream) {
  const float* q    = (const float*)d_in[0];
  const float* kv   = (const float*)d_in[1];
  const float* mask = (const float*)d_in[2];
  const float* Wq   = (const float*)d_in[3];
  const float* bq   = (const float*)d_in[4];
  const float* Wk   = (const float*)d_in[5];
  const float* bk   = (const float*)d_in[6];
  const float* Wv   = (const float*)d_in[7];
  const float* bv   = (const float*)d_in[8];
  float* out = (float*)d_out;

  // workspace layout (bf16 elems): Xq, Xkv, Q, K, Vt (4,194,304 each), Wt (3,145,728)
  uint16_t* Xq  = (uint16_t*)d_ws;
  uint16_t* Xkv = Xq + 4194304;
  uint16_t* Qm  = Xkv + 4194304;
  uint16_t* Km  = Qm + 4194304;
  uint16_t* Vtm = Km + 4194304;
  uint16_t* Wt  = Vtm + 4194304;

  hipLaunchKernelGGL(k_convert, dim3(2048, 2), dim3(256), 0, stream, q, kv, Xq, Xkv);
  hipLaunchKernelGGL(k_wtrans, dim3(16, 48), dim3(256), 0, stream, Wq, Wk, Wv, Wt);
  hipLaunchKernelGGL(k_proj, dim3(32, 48), dim3(256), 0, stream,
                     Xq, Xkv, Wt, bq, bk, bv, Qm, Km, Vtm);
  hipLaunchKernelGGL(k_attn, dim3(16, 32), dim3(256), 0, stream, Qm, Km, Vtm, mask, out);
}

// Round 2
// 154.798 us; speedup vs baseline: 1.0513x; 1.0513x over previous
//
#include <hip/hip_runtime.h>
#include <stdint.h>

// Problem: B=2, S=2048, D=1024, H=16, DH=64. fp32 in/out, bf16 MFMA inside.

typedef __attribute__((ext_vector_type(8))) short bf16x8;   // 8 bf16 = 4 VGPR
typedef __attribute__((ext_vector_type(4))) float f32x4;    // MFMA C/D

__device__ __forceinline__ uint16_t f2bf(float f) {
  union { float f; uint32_t u; } c; c.f = f;
  uint32_t u = c.u;
  return (uint16_t)((u + 0x7fffu + ((u >> 16) & 1u)) >> 16);  // RNE
}

__device__ __forceinline__ void gload_lds16(const void* g, void* l) {
  __builtin_amdgcn_global_load_lds(
      (const __attribute__((address_space(1))) uint32_t*)g,
      (__attribute__((address_space(3))) uint32_t*)l, 16, 0, 0);
}

// Stage 8 rows x 64 cols (bf16) into LDS tile rows [r0..r0+8), pitch 128B.
// XOR-swizzle: element (row,col) lands at byte row*128 + ((col/8)*16 ^ ((row&7)<<4)) + (col%8)*2.
// global_load_lds writes linearly (base + lane*16), so we pre-swizzle the SOURCE granule.
// Requires r0 % 8 == 0.
__device__ __forceinline__ void stage8(const uint16_t* gbase /*row r0, col 0*/,
                                       int pitch /*elems*/,
                                       uint16_t* lds_r0 /*&tile[r0*64], wave-uniform*/,
                                       int lane) {
  int r = lane >> 3;            // 0..7 row within group
  int gcol = lane & 7;          // 16B granule within row
  int gsrc = gcol ^ r;          // involution; r == (row&7) since r0%8==0
  const uint16_t* src = gbase + (size_t)r * pitch + gsrc * 8;
  gload_lds16(src, lds_r0);
}

// Read an 8-element k-contiguous MFMA fragment (A or B operand) from a swizzled
// [rows][64] bf16 LDS tile. granule = ks*4 + (lane>>4); k-slots are a consistent
// permutation across both operands, so MFMA result is exact regardless of HW k-order.
__device__ __forceinline__ bf16x8 frag_read(const uint16_t* tile, int row, int granule) {
  int off = row * 128 + ((granule << 4) ^ ((row & 7) << 4));
  return *(const bf16x8*)((const char*)tile + off);
}

// ---------------- kernel 0a: fp32 -> bf16 convert of q / kv inputs ----------------
__global__ __launch_bounds__(256) void k_convert(const float* __restrict__ q,
                                                 const float* __restrict__ kv,
                                                 uint16_t* __restrict__ oq,
                                                 uint16_t* __restrict__ okv) {
  const float* src = blockIdx.y ? kv : q;
  uint16_t* dst = blockIdx.y ? okv : oq;
  size_t i = ((size_t)blockIdx.x * 256 + threadIdx.x) * 8;
  float4 a = *(const float4*)(src + i);
  float4 b = *(const float4*)(src + i + 4);
  uint16_t r[8];
  r[0] = f2bf(a.x); r[1] = f2bf(a.y); r[2] = f2bf(a.z); r[3] = f2bf(a.w);
  r[4] = f2bf(b.x); r[5] = f2bf(b.y); r[6] = f2bf(b.z); r[7] = f2bf(b.w);
  *(uint4*)(dst + i) = *(uint4*)r;
}

// ---------------- kernel 0b: weight transpose W(h,d,n) fp32 -> Wt(mat,h,n,d) bf16 ----------------
__global__ __launch_bounds__(256) void k_wtrans(const float* __restrict__ Wq,
                                                const float* __restrict__ Wk,
                                                const float* __restrict__ Wv,
                                                uint16_t* __restrict__ Wt) {
  __shared__ uint16_t t[64][72];           // [n][d-local], padded
  int mat = blockIdx.y >> 4;
  int h = blockIdx.y & 15;
  int d0 = blockIdx.x * 64;
  const float* W = (mat == 0) ? Wq : (mat == 1) ? Wk : Wv;
  int tid = threadIdx.x;
  for (int p = 0; p < 4; p++) {
    int idx = tid + p * 256;               // 0..1023 float4s
    int row = idx >> 4;                    // d-local 0..63
    int c4 = idx & 15;                     // n-chunk of 4
    float4 v = *(const float4*)(W + ((size_t)h * 1024 + d0 + row) * 64 + c4 * 4);
    t[c4 * 4 + 0][row] = f2bf(v.x);
    t[c4 * 4 + 1][row] = f2bf(v.y);
    t[c4 * 4 + 2][row] = f2bf(v.z);
    t[c4 * 4 + 3][row] = f2bf(v.w);
  }
  __syncthreads();
  int n = tid >> 2, dc = tid & 3;
  uint16_t tmp[16];
  for (int i = 0; i < 16; i++) tmp[i] = t[n][dc * 16 + i];
  uint16_t* dst = Wt + ((size_t)(mat * 16 + h) * 64 + n) * 1024 + d0 + dc * 16;
  *(uint4*)(dst) = *(uint4*)(tmp);
  *(uint4*)(dst + 8) = *(uint4*)(tmp + 8);
}

// ---------------- kernel 1: QKV projection GEMM (two heads per block) ----------------
// Per block: 128(M) x 128(N = 2 heads x DH) for one (mat, head-pair). K=1024, BK=64, dbuf.
// Q,K stored (b,h,s,dh) bf16;  V stored transposed (b,h,dh,s) bf16 for the PV step.
__global__ __launch_bounds__(256, 2) void k_proj(const uint16_t* __restrict__ Xq,
                                                 const uint16_t* __restrict__ Xkv,
                                                 const uint16_t* __restrict__ Wt,
                                                 const float* __restrict__ bq,
                                                 const float* __restrict__ bk,
                                                 const float* __restrict__ bv,
                                                 uint16_t* __restrict__ Qm,
                                                 uint16_t* __restrict__ Km,
                                                 uint16_t* __restrict__ Vtm) {
  __shared__ uint16_t At[2][128 * 64];
  __shared__ uint16_t Bt[2][128 * 64];
  int mb = blockIdx.x;
  int mat = blockIdx.y / 8;                // 0..2
  int h0 = (blockIdx.y % 8) * 2;           // first head of the pair
  int tid = threadIdx.x, w = tid >> 6, lane = tid & 63;
  const uint16_t* X = (mat == 0) ? Xq : Xkv;
  const uint16_t* Wh = Wt + (size_t)(mat * 16 + h0) * (64 * 1024);  // 128 rows (2 heads)
  const float* bias = (mat == 0) ? bq : (mat == 1) ? bk : bv;
  int m0 = mb * 128;
  int rgrp = lane >> 4, cl = lane & 15;

  f32x4 acc[2][8];
#pragma unroll
  for (int mf = 0; mf < 2; mf++)
#pragma unroll
    for (int nf = 0; nf < 8; nf++)
#pragma unroll
      for (int j = 0; j < 4; j++) acc[mf][nf][j] = 0.0f;

  // prologue: stage kt=0
#pragma unroll
  for (int i = 0; i < 4; i++) {
    int r0 = w * 32 + i * 8;
    stage8(X + (size_t)(m0 + r0) * 1024, 1024, &At[0][r0 * 64], lane);
    stage8(Wh + (size_t)r0 * 1024, 1024, &Bt[0][r0 * 64], lane);
  }

  for (int kt = 0; kt < 16; kt++) {
    __syncthreads();           // staged tile kt ready (implicit vmcnt drain)
    if (kt < 15) {
      int nb = (kt + 1) & 1, k0 = (kt + 1) * 64;
#pragma unroll
      for (int i = 0; i < 4; i++) {
        int r0 = w * 32 + i * 8;
        stage8(X + (size_t)(m0 + r0) * 1024 + k0, 1024, &At[nb][r0 * 64], lane);
        stage8(Wh + (size_t)r0 * 1024 + k0, 1024, &Bt[nb][r0 * 64], lane);
      }
    }
    const uint16_t* a_t = At[kt & 1];
    const uint16_t* b_t = Bt[kt & 1];
    bf16x8 af[2][2], bfr[8][2];
#pragma unroll
    for (int mf = 0; mf < 2; mf++)
#pragma unroll
      for (int ks = 0; ks < 2; ks++)
        af[mf][ks] = frag_read(a_t, w * 32 + mf * 16 + cl, ks * 4 + rgrp);
#pragma unroll
    for (int nf = 0; nf < 8; nf++)
#pragma unroll
      for (int ks = 0; ks < 2; ks++)
        bfr[nf][ks] = frag_read(b_t, nf * 16 + cl, ks * 4 + rgrp);
    __builtin_amdgcn_s_setprio(1);
#pragma unroll
    for (int mf = 0; mf < 2; mf++)
#pragma unroll
      for (int nf = 0; nf < 8; nf++)
#pragma unroll
        for (int ks = 0; ks < 2; ks++)
          acc[mf][nf] = __builtin_amdgcn_mfma_f32_16x16x32_bf16(af[mf][ks], bfr[nf][ks], acc[mf][nf], 0, 0, 0);
    __builtin_amdgcn_s_setprio(0);
  }

  // epilogue: add bias, write bf16. C/D: col=lane&15, row=(lane>>4)*4+j (verified layout)
#pragma unroll
  for (int mf = 0; mf < 2; mf++)
#pragma unroll
    for (int nf = 0; nf < 8; nf++) {
      int col = nf * 16 + cl;              // 0..127 across the head pair
      int hh = h0 + (col >> 6);
      int c = col & 63;
      float bb = bias[hh * 64 + c];
      if (mat < 2) {
        uint16_t* dstbuf = (mat == 0) ? Qm : Km;
#pragma unroll
        for (int j = 0; j < 4; j++) {
          int row = m0 + w * 32 + mf * 16 + rgrp * 4 + j;
          int b = row >> 11, s = row & 2047;
          dstbuf[((size_t)(b * 16 + hh) * 2048 + s) * 64 + c] = f2bf(acc[mf][nf][j] + bb);
        }
      } else {
        int row0 = m0 + w * 32 + mf * 16 + rgrp * 4;
        int b = row0 >> 11, s0 = row0 & 2047;
        uint16_t pk[4];
#pragma unroll
        for (int j = 0; j < 4; j++) pk[j] = f2bf(acc[mf][nf][j] + bb);
        uint16_t* dst = Vtm + ((size_t)(b * 16 + hh) * 64 + c) * 2048 + s0;
        *(uint64_t*)dst = *(uint64_t*)pk;   // 4 consecutive s, 8B aligned
      }
    }
}

// ---------------- kernel 2: flash attention (transposed S / O) ----------------
// Block: (q-block of 128, bh). 4 waves x 32 q-rows. KVBLK=64, K/V double-buffered.
// S^T = mfma(K, Q): lane holds S[q = qf*16+cl][t = tf*16 + rgrp*4 + j] -> t contiguous in j.
// O^T = mfma(V^T, P): lane holds O[q = qf*16+cl][dh = dhf*16 + rgrp*4 + j].
__global__ __launch_bounds__(256, 2) void k_attn(const uint16_t* __restrict__ Qm,
                                                 const uint16_t* __restrict__ Km,
                                                 const uint16_t* __restrict__ Vtm,
                                                 const float* __restrict__ mask,
                                                 float* __restrict__ out) {
  __shared__ uint16_t Kt[2][64 * 64];
  __shared__ uint16_t Vt[2][64 * 64];
  __shared__ uint16_t Pt[128 * 64];
  int qb = blockIdx.x, bh = blockIdx.y;
  int b = bh >> 4, h = bh & 15;
  int tid = threadIdx.x, w = tid >> 6, lane = tid & 63;
  const uint16_t* Qbh = Qm + (size_t)bh * (2048 * 64);
  const uint16_t* Kbh = Km + (size_t)bh * (2048 * 64);
  const uint16_t* Vbh = Vtm + (size_t)bh * (64 * 2048);
  const float* maskb = mask + (size_t)b * (2048 * 2048);
  int q0 = qb * 128 + w * 32;
  int rgrp = lane >> 4, cl = lane & 15;
  uint16_t* Pw = Pt + w * 32 * 64;         // wave-local 32-row P region

  // Q fragments (B-operand of swapped QK^T), held in registers for all tiles
  bf16x8 qfr[2][2];
#pragma unroll
  for (int qf = 0; qf < 2; qf++)
#pragma unroll
    for (int ks = 0; ks < 2; ks++)
      qfr[qf][ks] = *(const bf16x8*)(Qbh + (size_t)(q0 + qf * 16 + cl) * 64 + (ks * 4 + rgrp) * 8);

  // per-lane mask row base (q = q0 + qf*16 + cl)
  const float* mrow_p[2];
#pragma unroll
  for (int qf = 0; qf < 2; qf++) mrow_p[qf] = maskb + (size_t)(q0 + qf * 16 + cl) * 2048;

  f32x4 oacc[4][2];                        // [dhf][qf]
  float mrow[2] = {-1e30f, -1e30f}, lrow[2] = {0.0f, 0.0f};
#pragma unroll
  for (int dhf = 0; dhf < 4; dhf++)
#pragma unroll
    for (int qf = 0; qf < 2; qf++)
#pragma unroll
      for (int j = 0; j < 4; j++) oacc[dhf][qf][j] = 0.0f;

  // prologue: stage tile 0
#pragma unroll
  for (int i = 0; i < 2; i++) {
    int r0 = w * 16 + i * 8;
    stage8(Kbh + (size_t)r0 * 64, 64, &Kt[0][r0 * 64], lane);
    stage8(Vbh + (size_t)r0 * 2048, 2048, &Vt[0][r0 * 64], lane);
  }

  for (int ti = 0; ti < 32; ti++) {
    __syncthreads();           // tile ti staged; prev tile's LDS reads done
    if (ti < 31) {
      int nb = (ti + 1) & 1, t0n = (ti + 1) * 64;
#pragma unroll
      for (int i = 0; i < 2; i++) {
        int r0 = w * 16 + i * 8;
        stage8(Kbh + (size_t)(t0n + r0) * 64, 64, &Kt[nb][r0 * 64], lane);
        stage8(Vbh + (size_t)r0 * 2048 + t0n, 2048, &Vt[nb][r0 * 64], lane);
      }
    }
    const uint16_t* kt = Kt[ti & 1];
    const uint16_t* vt = Vt[ti & 1];
    int t0 = ti * 64;

    // S^T = K Q^T : sc[tf][qf], row=t local, col=q local
    f32x4 sc[4][2];
#pragma unroll
    for (int tf = 0; tf < 4; tf++)
#pragma unroll
      for (int qf = 0; qf < 2; qf++)
#pragma unroll
        for (int j = 0; j < 4; j++) sc[tf][qf][j] = 0.0f;
    bf16x8 kf[4][2];
#pragma unroll
    for (int tf = 0; tf < 4; tf++)
#pragma unroll
      for (int ks = 0; ks < 2; ks++)
        kf[tf][ks] = frag_read(kt, tf * 16 + cl, ks * 4 + rgrp);
    __builtin_amdgcn_s_setprio(1);
#pragma unroll
    for (int tf = 0; tf < 4; tf++)
#pragma unroll
      for (int qf = 0; qf < 2; qf++)
#pragma unroll
        for (int ks = 0; ks < 2; ks++)
          sc[tf][qf] = __builtin_amdgcn_mfma_f32_16x16x32_bf16(kf[tf][ks], qfr[qf][ks], sc[tf][qf], 0, 0, 0);
    __builtin_amdgcn_s_setprio(0);

    // scale + mask (t contiguous in j -> float4 mask loads)
#pragma unroll
    for (int tf = 0; tf < 4; tf++)
#pragma unroll
      for (int qf = 0; qf < 2; qf++) {
        float4 mv = *(const float4*)(mrow_p[qf] + t0 + tf * 16 + rgrp * 4);
        sc[tf][qf][0] = fmaf(sc[tf][qf][0], 0.125f, mv.x);
        sc[tf][qf][1] = fmaf(sc[tf][qf][1], 0.125f, mv.y);
        sc[tf][qf][2] = fmaf(sc[tf][qf][2], 0.125f, mv.z);
        sc[tf][qf][3] = fmaf(sc[tf][qf][3], 0.125f, mv.w);
      }

    // row max over t: 16 in-lane values + 2 shuffles (lanes cl, cl+16, cl+32, cl+48)
    float pmax[2];
#pragma unroll
    for (int qf = 0; qf < 2; qf++) {
      float v0 = fmaxf(fmaxf(sc[0][qf][0], sc[0][qf][1]), fmaxf(sc[0][qf][2], sc[0][qf][3]));
      float v1 = fmaxf(fmaxf(sc[1][qf][0], sc[1][qf][1]), fmaxf(sc[1][qf][2], sc[1][qf][3]));
      float v2 = fmaxf(fmaxf(sc[2][qf][0], sc[2][qf][1]), fmaxf(sc[2][qf][2], sc[2][qf][3]));
      float v3 = fmaxf(fmaxf(sc[3][qf][0], sc[3][qf][1]), fmaxf(sc[3][qf][2], sc[3][qf][3]));
      pmax[qf] = fmaxf(fmaxf(v0, v1), fmaxf(v2, v3));
    }
#pragma unroll
    for (int qf = 0; qf < 2; qf++) {
      pmax[qf] = fmaxf(pmax[qf], __shfl_xor(pmax[qf], 16, 64));
      pmax[qf] = fmaxf(pmax[qf], __shfl_xor(pmax[qf], 32, 64));
    }

    // defer-max (T13): skip O/l rescale while max growth <= 8 (p bounded by e^8)
    bool skip = __all((pmax[0] <= mrow[0] + 8.0f) && (pmax[1] <= mrow[1] + 8.0f));
    if (!skip) {
      float fac[2];
#pragma unroll
      for (int qf = 0; qf < 2; qf++) {
        float mn = fmaxf(mrow[qf], pmax[qf]);
        fac[qf] = __expf(mrow[qf] - mn);
        mrow[qf] = mn;
        lrow[qf] *= fac[qf];
      }
#pragma unroll
      for (int dhf = 0; dhf < 4; dhf++)
#pragma unroll
        for (int qf = 0; qf < 2; qf++)
#pragma unroll
          for (int j = 0; j < 4; j++) oacc[dhf][qf][j] *= fac[qf];
    }

    // P = exp(S - m): accumulate row sums, pack 4 bf16 along t, one ds_write_b64 each
    float ps[2] = {0.0f, 0.0f};
#pragma unroll
    for (int tf = 0; tf < 4; tf++)
#pragma unroll
      for (int qf = 0; qf < 2; qf++) {
        float p0 = __expf(sc[tf][qf][0] - mrow[qf]);
        float p1 = __expf(sc[tf][qf][1] - mrow[qf]);
        float p2 = __expf(sc[tf][qf][2] - mrow[qf]);
        float p3 = __expf(sc[tf][qf][3] - mrow[qf]);
        ps[qf] += (p0 + p1) + (p2 + p3);
        uint32_t pk0 = (uint32_t)f2bf(p0) | ((uint32_t)f2bf(p1) << 16);
        uint32_t pk1 = (uint32_t)f2bf(p2) | ((uint32_t)f2bf(p3) << 16);
        int qw = qf * 16 + cl;
        int off = qw * 128 + ((((tf * 2 + (rgrp >> 1)) << 4)) ^ ((qw & 7) << 4)) + (rgrp & 1) * 8;
        uint2 pv; pv.x = pk0; pv.y = pk1;
        *(uint2*)((char*)Pw + off) = pv;
      }
#pragma unroll
    for (int qf = 0; qf < 2; qf++) {
      ps[qf] += __shfl_xor(ps[qf], 16, 64);
      ps[qf] += __shfl_xor(ps[qf], 32, 64);
      lrow[qf] += ps[qf];
    }

    // order P stores before P fragment loads (same-wave DS ops are in-order in HW)
    asm volatile("" ::: "memory");

    // O^T += V^T P : A = V^T rows (dh), B = P rows (q), k = t
    bf16x8 vf[4][2], pf[2][2];
#pragma unroll
    for (int dhf = 0; dhf < 4; dhf++)
#pragma unroll
      for (int ks = 0; ks < 2; ks++)
        vf[dhf][ks] = frag_read(vt, dhf * 16 + cl, ks * 4 + rgrp);
#pragma unroll
    for (int qf = 0; qf < 2; qf++)
#pragma unroll
      for (int ks = 0; ks < 2; ks++)
        pf[qf][ks] = frag_read(Pw, qf * 16 + cl, ks * 4 + rgrp);
    __builtin_amdgcn_s_setprio(1);
#pragma unroll
    for (int dhf = 0; dhf < 4; dhf++)
#pragma unroll
      for (int qf = 0; qf < 2; qf++)
#pragma unroll
        for (int ks = 0; ks < 2; ks++)
          oacc[dhf][qf] = __builtin_amdgcn_mfma_f32_16x16x32_bf16(vf[dhf][ks], pf[qf][ks], oacc[dhf][qf], 0, 0, 0);
    __builtin_amdgcn_s_setprio(0);
  }

  // epilogue: out[b][q][h*64 + dh] = O^T[dh][q] / l[q]; dh contiguous in j -> float4 stores
#pragma unroll
  for (int qf = 0; qf < 2; qf++) {
    float inv = __builtin_amdgcn_rcpf(lrow[qf]);
    int q = q0 + qf * 16 + cl;
    float* orow = out + ((size_t)b * 2048 + q) * 1024 + h * 64;
#pragma unroll
    for (int dhf = 0; dhf < 4; dhf++) {
      float4 o;
      o.x = oacc[dhf][qf][0] * inv;
      o.y = oacc[dhf][qf][1] * inv;
      o.z = oacc[dhf][qf][2] * inv;
      o.w = oacc[dhf][qf][3] * inv;
      *(float4*)(orow + dhf * 16 + rgrp * 4) = o;
    }
  }
}

extern "C" void kernel_launch(void* const* d_in, const int* in_sizes, int n_in,
                              void* d_out, int out_size, void* d_ws, size_t ws_size,
                              hipStream_t stream) {
  const float* q    = (const float*)d_in[0];
  const float* kv   = (const float*)d_in[1];
  const float* mask = (const float*)d_in[2];
  const float* Wq   = (const float*)d_in[3];
  const float* bq   = (const float*)d_in[4];
  const float* Wk   = (const float*)d_in[5];
  const float* bk   = (const float*)d_in[6];
  const float* Wv   = (const float*)d_in[7];
  const float* bv   = (const float*)d_in[8];
  float* out = (float*)d_out;

  // workspace layout (bf16 elems): Xq, Xkv, Q, K, Vt (4,194,304 each), Wt (3,145,728)
  uint16_t* Xq  = (uint16_t*)d_ws;
  uint16_t* Xkv = Xq + 4194304;
  uint16_t* Qm  = Xkv + 4194304;
  uint16_t* Km  = Qm + 4194304;
  uint16_t* Vtm = Km + 4194304;
  uint16_t* Wt  = Vtm + 4194304;

  hipLaunchKernelGGL(k_convert, dim3(2048, 2), dim3(256), 0, stream, q, kv, Xq, Xkv);
  hipLaunchKernelGGL(k_wtrans, dim3(16, 48), dim3(256), 0, stream, Wq, Wk, Wv, Wt);
  hipLaunchKernelGGL(k_proj, dim3(32, 24), dim3(256), 0, stream,
                     Xq, Xkv, Wt, bq, bk, bv, Qm, Km, Vtm);
  hipLaunchKernelGGL(k_attn, dim3(16, 32), dim3(256), 0, stream, Qm, Km, Vtm, mask, out);
}